// Round 4
// baseline (50.326 us; speedup 1.0000x reference)
//
#include <hip/hip_runtime.h>

#define S_DIV 14.0f
#define N_BATCH 4096
#define NCELL (4096 * 14 * 14)   // 802816
#define CELLS_PER_BLOCK 256
#define NBLOCKS (NCELL / CELLS_PER_BLOCK)   // 3136

// ---------------------------------------------------------------------------
// Kernel 1: detect mask storage layout.
// flag: 0 = int32 (0/1), 1 = float32 (0.0/1.0), 2 = uint8 (numpy bool)
// ---------------------------------------------------------------------------
__global__ void detect_flag(const unsigned int* __restrict__ mask_words,
                            int* __restrict__ flag) {
    __shared__ int s_notInt, s_notFloat;
    const int tid = threadIdx.x;
    if (tid == 0) { s_notInt = 0; s_notFloat = 0; }
    __syncthreads();
    int notInt = 0, notFloat = 0;
    for (int i = tid; i < 4096; i += 256) {
        const unsigned int u = mask_words[i];
        if (u > 1u) notInt = 1;
        if (u != 0u && u != 0x3F800000u) notFloat = 1;
    }
    if (notInt)   atomicOr(&s_notInt, 1);
    if (notFloat) atomicOr(&s_notFloat, 1);
    __syncthreads();
    if (tid == 0) *flag = (!s_notInt) ? 0 : ((!s_notFloat) ? 1 : 2);
}

// ---------------------------------------------------------------------------
// Kernel 2: main loss. Block = 256 cells. pred streamed as coalesced float4;
// cls-channel components (j>=10) are consumed IN the streaming loop (scalar
// tcls load + fma, mf from LDS); box components (j<10) scattered to a 10 KB
// LDS tile. No tcls staging, no atomics.
// ---------------------------------------------------------------------------
__device__ __forceinline__ float iou_xyxy(const float a0, const float a1,
                                          const float a2, const float a3,
                                          const float b0, const float b1,
                                          const float b2, const float b3) {
    const float ltx = fmaxf(a0, b0), lty = fmaxf(a1, b1);
    const float rbx = fminf(a2, b2), rby = fminf(a3, b3);
    const float wx = fmaxf(rbx - ltx, 0.0f), wy = fmaxf(rby - lty, 0.0f);
    const float inter = wx * wy;
    const float area_a = (a2 - a0) * (a3 - a1);
    const float area_b = (b2 - b0) * (b3 - b1);
    return inter / (area_a + area_b - inter);
}

__global__ __launch_bounds__(256) void yolo_loss_main(
    const float* __restrict__ pred,
    const float* __restrict__ tbox,
    const float* __restrict__ tcls,
    const void* __restrict__ maskp,
    const int* __restrict__ flagp,
    float4* __restrict__ partial) {

    __shared__ __align__(16) float s_box[CELLS_PER_BLOCK * 10];  // 10 KB
    __shared__ float s_mf[CELLS_PER_BLOCK];                      // 1 KB
    __shared__ float s_red[4][4];

    const int t = threadIdx.x;
    const int cell0 = blockIdx.x * CELLS_PER_BLOCK;
    const int idx = cell0 + t;
    const int flag = *flagp;

    // ---- mask -> LDS (needed by the streaming cls fma) ----
    bool m;
    if (flag == 0)      m = ((const int*)maskp)[idx] != 0;
    else if (flag == 1) m = ((const float*)maskp)[idx] != 0.0f;
    else                m = ((const unsigned char*)maskp)[idx] != 0;
    const float mf = m ? 1.0f : 0.0f;
    s_mf[t] = mf;

    // tbox direct (coalesced float4-per-cell)
    const float4 tb = ((const float4*)tbox)[idx];

    __syncthreads();

    // ---- stream pred (1920 float4 per block), fold cls loss in-line ----
    float cls = 0.0f;
    const float4* pg = (const float4*)(pred + (size_t)cell0 * 30);
    const float* tcb = tcls + (size_t)cell0 * 20;
    for (int e = t; e < CELLS_PER_BLOCK * 30 / 4; e += 256) {
        const float4 v4 = pg[e];
        const float vv[4] = {v4.x, v4.y, v4.z, v4.w};
        const int f0 = 4 * e;
        #pragma unroll
        for (int kk = 0; kk < 4; ++kk) {
            const int f = f0 + kk;
            const int c = f / 30;          // magic-mul
            const int j = f - c * 30;
            const float v = vv[kk];
            if (j < 10) {
                s_box[c * 10 + j] = v;
            } else {
                const float d = v - tcb[c * 20 + (j - 10)];
                cls += s_mf[c] * d * d;
            }
        }
    }
    __syncthreads();

    // ---- per-cell box math from LDS ----
    float pr[10];
    #pragma unroll
    for (int i = 0; i < 10; ++i) pr[i] = s_box[t * 10 + i];

    float noobj = (1.0f - mf) * (pr[4] * pr[4] + pr[9] * pr[9]);

    const float b1x0 = pr[0] / S_DIV - 0.5f * pr[2];
    const float b1y0 = pr[1] / S_DIV - 0.5f * pr[3];
    const float b1x1 = pr[0] / S_DIV + 0.5f * pr[2];
    const float b1y1 = pr[1] / S_DIV + 0.5f * pr[3];
    const float b2x0 = pr[5] / S_DIV - 0.5f * pr[7];
    const float b2y0 = pr[6] / S_DIV - 0.5f * pr[8];
    const float b2x1 = pr[5] / S_DIV + 0.5f * pr[7];
    const float b2y1 = pr[6] / S_DIV + 0.5f * pr[8];
    const float btx0 = tb.x / S_DIV - 0.5f * tb.z;
    const float bty0 = tb.y / S_DIV - 0.5f * tb.w;
    const float btx1 = tb.x / S_DIV + 0.5f * tb.z;
    const float bty1 = tb.y / S_DIV + 0.5f * tb.w;

    const float i1 = iou_xyxy(b1x0, b1y0, b1x1, b1y1, btx0, bty0, btx1, bty1);
    const float i2 = iou_xyxy(b2x0, b2y0, b2x1, b2y1, btx0, bty0, btx1, bty1);

    const bool take1 = i1 > i2;
    const float best_iou = take1 ? i1 : i2;
    const float bx = take1 ? pr[0] : pr[5];
    const float by = take1 ? pr[1] : pr[6];
    const float bw = take1 ? pr[2] : pr[7];
    const float bh = take1 ? pr[3] : pr[8];
    const float bc = take1 ? pr[4] : pr[9];

    const float dx = bx - tb.x;
    const float dy = by - tb.y;
    const float pw = m ? sqrtf(bw) : 1.0f;
    const float ph = m ? sqrtf(bh) : 1.0f;
    const float tw = m ? sqrtf(tb.z) : 1.0f;
    const float th = m ? sqrtf(tb.w) : 1.0f;
    float reg = mf * (dx * dx + dy * dy)
              + mf * ((pw - tw) * (pw - tw) + (ph - th) * (ph - th));

    const float dc = bc - best_iou;
    float conf = mf * dc * dc;

    // ---- wave + block reduction ----
    #pragma unroll
    for (int off = 32; off > 0; off >>= 1) {
        reg   += __shfl_down(reg,   off);
        conf  += __shfl_down(conf,  off);
        noobj += __shfl_down(noobj, off);
        cls   += __shfl_down(cls,   off);
    }
    const int lane = t & 63;
    const int wid  = t >> 6;
    if (lane == 0) {
        s_red[0][wid] = reg; s_red[1][wid] = conf;
        s_red[2][wid] = noobj; s_red[3][wid] = cls;
    }
    __syncthreads();
    if (t == 0) {
        float r = 0.0f, cf = 0.0f, no = 0.0f, cl = 0.0f;
        #pragma unroll
        for (int w = 0; w < 4; ++w) {
            r += s_red[0][w]; cf += s_red[1][w];
            no += s_red[2][w]; cl += s_red[3][w];
        }
        partial[blockIdx.x] = make_float4(r, cf, no, cl);
    }
}

// ---------------------------------------------------------------------------
// Kernel 3: finalize — reduce block partials (double accum), normalize.
// ---------------------------------------------------------------------------
__global__ __launch_bounds__(256) void yolo_finalize(
    const float4* __restrict__ partial,
    float* __restrict__ out) {
    const int t = threadIdx.x;
    double r = 0.0, cf = 0.0, no = 0.0, cl = 0.0;
    for (int i = t; i < NBLOCKS; i += 256) {
        const float4 p = partial[i];
        r += (double)p.x; cf += (double)p.y; no += (double)p.z; cl += (double)p.w;
    }
    #pragma unroll
    for (int off = 32; off > 0; off >>= 1) {
        r  += __shfl_down(r,  off);
        cf += __shfl_down(cf, off);
        no += __shfl_down(no, off);
        cl += __shfl_down(cl, off);
    }
    __shared__ double s[4][4];
    const int lane = t & 63;
    const int wid  = t >> 6;
    if (lane == 0) { s[0][wid] = r; s[1][wid] = cf; s[2][wid] = no; s[3][wid] = cl; }
    __syncthreads();
    if (t == 0) {
        double R = 0, CF = 0, NO = 0, CL = 0;
        #pragma unroll
        for (int w = 0; w < 4; ++w) { R += s[0][w]; CF += s[1][w]; NO += s[2][w]; CL += s[3][w]; }
        const float invN = 1.0f / (float)N_BATCH;
        const float reg   = (float)R  * invN;
        const float conf  = (float)CF * invN;
        const float noobj = (float)NO * invN;
        const float cls   = (float)CL * invN;
        out[0] = 5.0f * reg + conf + 0.5f * noobj + cls;
        out[1] = reg;
        out[2] = conf;
        out[3] = noobj;
        out[4] = cls;
    }
}

extern "C" void kernel_launch(void* const* d_in, const int* in_sizes, int n_in,
                              void* d_out, int out_size, void* d_ws, size_t ws_size,
                              hipStream_t stream) {
    const float* pred = (const float*)d_in[0];
    const float* tbox = (const float*)d_in[1];
    const float* tcls = (const float*)d_in[2];
    const void*  mask = (const void*)d_in[3];
    float* out = (float*)d_out;

    float4* partial = (float4*)d_ws;                      // 3136 * 16 B
    int* flag = (int*)((char*)d_ws + NBLOCKS * sizeof(float4));

    detect_flag<<<1, 256, 0, stream>>>((const unsigned int*)mask, flag);
    yolo_loss_main<<<NBLOCKS, 256, 0, stream>>>(pred, tbox, tcls, mask, flag, partial);
    yolo_finalize<<<1, 256, 0, stream>>>(partial, out);
}

// Round 5
// 42.046 us; speedup vs baseline: 1.1969x; 1.1969x over previous
//
#include <hip/hip_runtime.h>

#define S_DIV 14.0f
#define N_BATCH 4096
#define NCELL (4096 * 14 * 14)   // 802816
#define CELLS_PER_BLOCK 256
#define NBLOCKS (NCELL / CELLS_PER_BLOCK)   // 3136

// ---------------------------------------------------------------------------
// Kernel 1: detect mask storage layout.
// flag: 0 = int32 (0/1), 1 = float32 (0.0/1.0), 2 = uint8 (numpy bool)
// ---------------------------------------------------------------------------
__global__ void detect_flag(const unsigned int* __restrict__ mask_words,
                            int* __restrict__ flag) {
    __shared__ int s_notInt, s_notFloat;
    const int tid = threadIdx.x;
    if (tid == 0) { s_notInt = 0; s_notFloat = 0; }
    __syncthreads();
    int notInt = 0, notFloat = 0;
    for (int i = tid; i < 4096; i += 256) {
        const unsigned int u = mask_words[i];
        if (u > 1u) notInt = 1;
        if (u != 0u && u != 0x3F800000u) notFloat = 1;
    }
    if (notInt)   atomicOr(&s_notInt, 1);
    if (notFloat) atomicOr(&s_notFloat, 1);
    __syncthreads();
    if (tid == 0) *flag = (!s_notInt) ? 0 : ((!s_notFloat) ? 1 : 2);
}

// ---------------------------------------------------------------------------
// Kernel 2: main loss. Block = 256 cells.
//   phase 1: pred -> LDS, pure coalesced float4 copy (no index math)
//   phase 2: tcls streamed as coalesced float4 (each float4 entirely inside
//            one cell since 20%4==0): one div-by-5 per float4, cls loss
//            accumulated against LDS-resident pred channels 10..29
//   phase 3: per-cell box math from LDS channels 0..9
// No atomics: one float4 partial per block.
// ---------------------------------------------------------------------------
__device__ __forceinline__ float iou_xyxy(const float a0, const float a1,
                                          const float a2, const float a3,
                                          const float b0, const float b1,
                                          const float b2, const float b3) {
    const float ltx = fmaxf(a0, b0), lty = fmaxf(a1, b1);
    const float rbx = fminf(a2, b2), rby = fminf(a3, b3);
    const float wx = fmaxf(rbx - ltx, 0.0f), wy = fmaxf(rby - lty, 0.0f);
    const float inter = wx * wy;
    const float area_a = (a2 - a0) * (a3 - a1);
    const float area_b = (b2 - b0) * (b3 - b1);
    return inter / (area_a + area_b - inter);
}

__global__ __launch_bounds__(256) void yolo_loss_main(
    const float* __restrict__ pred,
    const float* __restrict__ tbox,
    const float* __restrict__ tcls,
    const void* __restrict__ maskp,
    const int* __restrict__ flagp,
    float4* __restrict__ partial) {

    __shared__ __align__(16) float s_pred[CELLS_PER_BLOCK * 30];  // 30 KB
    __shared__ float s_mf[CELLS_PER_BLOCK];                       // 1 KB
    __shared__ float s_red[4][4];

    const int t = threadIdx.x;
    const int cell0 = blockIdx.x * CELLS_PER_BLOCK;
    const int idx = cell0 + t;
    const int flag = *flagp;

    // ---- mask -> LDS + registers ----
    bool m;
    if (flag == 0)      m = ((const int*)maskp)[idx] != 0;
    else if (flag == 1) m = ((const float*)maskp)[idx] != 0.0f;
    else                m = ((const unsigned char*)maskp)[idx] != 0;
    const float mf = m ? 1.0f : 0.0f;
    s_mf[t] = mf;

    // tbox direct (coalesced float4-per-cell)
    const float4 tb = ((const float4*)tbox)[idx];

    // ---- phase 1: pred -> LDS, pure float4 copy ----
    {
        const float4* pg = (const float4*)(pred + (size_t)cell0 * 30);
        float4* sp = (float4*)s_pred;
        #pragma unroll
        for (int e = t; e < CELLS_PER_BLOCK * 30 / 4; e += 256) sp[e] = pg[e];
    }
    __syncthreads();

    // ---- phase 2: stream tcls (coalesced), cls loss vs LDS pred ----
    float cls = 0.0f;
    {
        const float4* cg = (const float4*)(tcls + (size_t)cell0 * 20);
        #pragma unroll
        for (int k = 0; k < 5; ++k) {
            const int e = t + k * 256;            // 1280 float4 total
            const float4 v4 = cg[e];
            const int c = e / 5;                  // one magic-div per float4
            const int j0 = (e - c * 5) * 4;       // 0,4,8,12,16
            const float* sp = &s_pred[c * 30 + 10 + j0];
            const float w = s_mf[c];
            float d0 = sp[0] - v4.x;
            float d1 = sp[1] - v4.y;
            float d2 = sp[2] - v4.z;
            float d3 = sp[3] - v4.w;
            cls += w * (d0 * d0 + d1 * d1 + d2 * d2 + d3 * d3);
        }
    }

    // ---- phase 3: per-cell box math from LDS ----
    float pr[10];
    #pragma unroll
    for (int i = 0; i < 10; ++i) pr[i] = s_pred[t * 30 + i];

    float noobj = (1.0f - mf) * (pr[4] * pr[4] + pr[9] * pr[9]);

    const float b1x0 = pr[0] / S_DIV - 0.5f * pr[2];
    const float b1y0 = pr[1] / S_DIV - 0.5f * pr[3];
    const float b1x1 = pr[0] / S_DIV + 0.5f * pr[2];
    const float b1y1 = pr[1] / S_DIV + 0.5f * pr[3];
    const float b2x0 = pr[5] / S_DIV - 0.5f * pr[7];
    const float b2y0 = pr[6] / S_DIV - 0.5f * pr[8];
    const float b2x1 = pr[5] / S_DIV + 0.5f * pr[7];
    const float b2y1 = pr[6] / S_DIV + 0.5f * pr[8];
    const float btx0 = tb.x / S_DIV - 0.5f * tb.z;
    const float bty0 = tb.y / S_DIV - 0.5f * tb.w;
    const float btx1 = tb.x / S_DIV + 0.5f * tb.z;
    const float bty1 = tb.y / S_DIV + 0.5f * tb.w;

    const float i1 = iou_xyxy(b1x0, b1y0, b1x1, b1y1, btx0, bty0, btx1, bty1);
    const float i2 = iou_xyxy(b2x0, b2y0, b2x1, b2y1, btx0, bty0, btx1, bty1);

    const bool take1 = i1 > i2;
    const float best_iou = take1 ? i1 : i2;
    const float bx = take1 ? pr[0] : pr[5];
    const float by = take1 ? pr[1] : pr[6];
    const float bw = take1 ? pr[2] : pr[7];
    const float bh = take1 ? pr[3] : pr[8];
    const float bc = take1 ? pr[4] : pr[9];

    const float dx = bx - tb.x;
    const float dy = by - tb.y;
    const float pw = m ? sqrtf(bw) : 1.0f;
    const float ph = m ? sqrtf(bh) : 1.0f;
    const float tw = m ? sqrtf(tb.z) : 1.0f;
    const float th = m ? sqrtf(tb.w) : 1.0f;
    float reg = mf * (dx * dx + dy * dy)
              + mf * ((pw - tw) * (pw - tw) + (ph - th) * (ph - th));

    const float dc = bc - best_iou;
    float conf = mf * dc * dc;

    // ---- wave + block reduction ----
    #pragma unroll
    for (int off = 32; off > 0; off >>= 1) {
        reg   += __shfl_down(reg,   off);
        conf  += __shfl_down(conf,  off);
        noobj += __shfl_down(noobj, off);
        cls   += __shfl_down(cls,   off);
    }
    const int lane = t & 63;
    const int wid  = t >> 6;
    if (lane == 0) {
        s_red[0][wid] = reg; s_red[1][wid] = conf;
        s_red[2][wid] = noobj; s_red[3][wid] = cls;
    }
    __syncthreads();
    if (t == 0) {
        float r = 0.0f, cf = 0.0f, no = 0.0f, cl = 0.0f;
        #pragma unroll
        for (int w = 0; w < 4; ++w) {
            r += s_red[0][w]; cf += s_red[1][w];
            no += s_red[2][w]; cl += s_red[3][w];
        }
        partial[blockIdx.x] = make_float4(r, cf, no, cl);
    }
}

// ---------------------------------------------------------------------------
// Kernel 3: finalize — reduce block partials (double accum), normalize.
// ---------------------------------------------------------------------------
__global__ __launch_bounds__(256) void yolo_finalize(
    const float4* __restrict__ partial,
    float* __restrict__ out) {
    const int t = threadIdx.x;
    double r = 0.0, cf = 0.0, no = 0.0, cl = 0.0;
    for (int i = t; i < NBLOCKS; i += 256) {
        const float4 p = partial[i];
        r += (double)p.x; cf += (double)p.y; no += (double)p.z; cl += (double)p.w;
    }
    #pragma unroll
    for (int off = 32; off > 0; off >>= 1) {
        r  += __shfl_down(r,  off);
        cf += __shfl_down(cf, off);
        no += __shfl_down(no, off);
        cl += __shfl_down(cl, off);
    }
    __shared__ double s[4][4];
    const int lane = t & 63;
    const int wid  = t >> 6;
    if (lane == 0) { s[0][wid] = r; s[1][wid] = cf; s[2][wid] = no; s[3][wid] = cl; }
    __syncthreads();
    if (t == 0) {
        double R = 0, CF = 0, NO = 0, CL = 0;
        #pragma unroll
        for (int w = 0; w < 4; ++w) { R += s[0][w]; CF += s[1][w]; NO += s[2][w]; CL += s[3][w]; }
        const float invN = 1.0f / (float)N_BATCH;
        const float reg   = (float)R  * invN;
        const float conf  = (float)CF * invN;
        const float noobj = (float)NO * invN;
        const float cls   = (float)CL * invN;
        out[0] = 5.0f * reg + conf + 0.5f * noobj + cls;
        out[1] = reg;
        out[2] = conf;
        out[3] = noobj;
        out[4] = cls;
    }
}

extern "C" void kernel_launch(void* const* d_in, const int* in_sizes, int n_in,
                              void* d_out, int out_size, void* d_ws, size_t ws_size,
                              hipStream_t stream) {
    const float* pred = (const float*)d_in[0];
    const float* tbox = (const float*)d_in[1];
    const float* tcls = (const float*)d_in[2];
    const void*  mask = (const void*)d_in[3];
    float* out = (float*)d_out;

    float4* partial = (float4*)d_ws;                      // 3136 * 16 B
    int* flag = (int*)((char*)d_ws + NBLOCKS * sizeof(float4));

    detect_flag<<<1, 256, 0, stream>>>((const unsigned int*)mask, flag);
    yolo_loss_main<<<NBLOCKS, 256, 0, stream>>>(pred, tbox, tcls, mask, flag, partial);
    yolo_finalize<<<1, 256, 0, stream>>>(partial, out);
}